// Round 15
// baseline (143.371 us; speedup 1.0000x reference)
//
#include <hip/hip_runtime.h>
#include <hip/hip_bf16.h>

// EmbeddingRNN via MFMA, round 15 = R14 (113.4us) + register-resident U tiles.
// KEY INSIGHT: the "128-VGPR law" (R2-R7) was occupancy-conditional — it held
// while LDS allowed 2 blocks/CU (budget 131072/1024 thr). Since R12, LDS
// 149.5KB forces 1 block/CU = 8 waves/CU, at which HW allows 256 VGPR/thread
// at the SAME occupancy (m69: waves/CU halves at vgpr 64/128/256).
// __launch_bounds__(512, 2) (= min 2 waves/EU, exactly the LDS-forced
// occupancy) tells the allocator so.
//  -> kt2,kt3,kt4 B-fragments persistent in registers (96 VGPR, loaded once).
//  -> global stream = kt5..7 + gather = 256KB/step (-43% vs R14's 448KB).
// Spill-meter gate: WRITE_SIZE == 8.2MB == out; if the cap holds at 128 this
// spills massively -> revert to R14 next round and declare roofline.

#define DD      256
#define G4      1024
#define NCHAR   155
#define TSTEPS  16
#define RTILE   32
#define NROWS   8192
#define NBLOCKS (NROWS / RTILE)   // 256
#define NTHREADS 512              // 8 waves; wave w owns d-slice [w*32, w*32+32)

typedef __attribute__((ext_vector_type(8))) short bf16x8;
typedef __attribute__((ext_vector_type(8))) unsigned short u16x8;
typedef __attribute__((ext_vector_type(4))) float f32x4;
typedef __attribute__((ext_vector_type(16))) _Float16 f16x16;

__device__ inline unsigned short f2bf_bits(float f) {
    __hip_bfloat16 h = __float2bfloat16(f);   // RTNE
    return *reinterpret_cast<unsigned short*>(&h);
}

__device__ inline float sigmoid_fast(float x) {
    return __builtin_amdgcn_rcpf(1.f + __expf(-x));
}

// ---------------- phase 0a: embWp8 = pack_bf16(emb @ W + b) ----------------
// value (char i, gate g, col d): w=d>>5, l15=d&15, nn=(d>>4)&1, nt=g*2+nn
// embWp8[ ((i*8 + w)*16 + l15)*8 + nt ]  (ushort bf16)
__global__ __launch_bounds__(256)
void embw_kernel(const float* __restrict__ emb, const float* __restrict__ W,
                 const float* __restrict__ b, unsigned short* __restrict__ embWp8) {
    const int i   = blockIdx.x;
    const int tid = threadIdx.x;
    float a0 = b[tid], a1 = b[256 + tid], a2 = b[512 + tid], a3 = b[768 + tid];
    const float* er = emb + i * DD;
    for (int k = 0; k < DD; ++k) {
        const float e = er[k];
        const float* wr = W + k * G4 + tid;
        a0 += e * wr[0];
        a1 += e * wr[256];
        a2 += e * wr[512];
        a3 += e * wr[768];
    }
    const int w = tid >> 5, l15 = tid & 15, nn = (tid >> 4) & 1;
    unsigned short* o = embWp8 + ((i * 8 + w) * 16 + l15) * 8 + nn;
    o[0] = f2bf_bits(a0); o[2] = f2bf_bits(a1);
    o[4] = f2bf_bits(a2); o[6] = f2bf_bits(a3);   // nt = g*2+nn
}

// ---------------- phase 0b: pack U into bf16 MFMA B-fragments ----------------
// up[((w*8 + kt)*8 + nt)*64 + lane]: lane l holds
//   U[kt*32+(l>>4)*8+j][g*256 + w*32 + nn*16 + (l&15)], nt=g*2+nn
__global__ __launch_bounds__(256)
void upack_kernel(const float* __restrict__ U, bf16x8* __restrict__ up) {
    const int gid  = blockIdx.x * 256 + threadIdx.x;   // 32768 total
    const int lane = gid & 63;
    const int nt   = (gid >> 6) & 7;
    const int kt   = (gid >> 9) & 7;
    const int w    = gid >> 12;
    const int g = nt >> 1, nn = nt & 1;
    const int col = g * 256 + w * 32 + nn * 16 + (lane & 15);
    const int k0  = kt * 32 + (lane >> 4) * 8;
    bf16x8 v;
#pragma unroll
    for (int j = 0; j < 8; ++j) v[j] = (short)f2bf_bits(U[(k0 + j) * G4 + col]);
    up[gid] = v;
}

// ---------------- phase 1: fused recurrence ----------------

#define LOADB(DST, KT)                                                          \
    _Pragma("unroll")                                                           \
    for (int nt = 0; nt < 8; ++nt) (DST)[nt] = upw[((KT) * 8 + nt) * 64 + lane];

#define AFR_LOAD(KT)                                                            \
        const int kb = ((KT) * 32 + lg * 8) * 2;                                \
        const int r0 = l15, r1 = 16 + l15;                                      \
        bf16x8 afr0 = *(const bf16x8*)(rbb + ((r0 * 512 + kb) ^ ((r0 & 7) << 4))); \
        bf16x8 afr1 = *(const bf16x8*)(rbb + ((r1 * 512 + kb) ^ ((r1 & 7) << 4)));

// kt from a register B-array (streamed or persistent)
#define AFR_MFMA(KT, BARR)                                                      \
    {   AFR_LOAD(KT)                                                            \
        _Pragma("unroll")                                                       \
        for (int nt = 0; nt < 8; ++nt) {                                        \
            acc[0][nt] = __builtin_amdgcn_mfma_f32_16x16x32_bf16(               \
                afr0, (BARR)[nt], acc[0][nt], 0, 0, 0);                         \
            acc[1][nt] = __builtin_amdgcn_mfma_f32_16x16x32_bf16(               \
                afr1, (BARR)[nt], acc[1][nt], 0, 0, 0);                         \
        }                                                                       \
    }

// kt KT entirely from an LDS-resident tile (8 nt)
#define AFR_LDSRES(KT, BASE)                                                    \
    {   AFR_LOAD(KT)                                                            \
        const char* bp = (const char*)(BASE) + w * 8192 + lane * 16;            \
        _Pragma("unroll")                                                       \
        for (int nt = 0; nt < 8; ++nt) {                                        \
            bf16x8 bf = *(const bf16x8*)(bp + nt * 1024);                       \
            acc[0][nt] = __builtin_amdgcn_mfma_f32_16x16x32_bf16(               \
                afr0, bf, acc[0][nt], 0, 0, 0);                                 \
            acc[1][nt] = __builtin_amdgcn_mfma_f32_16x16x32_bf16(               \
                afr1, bf, acc[1][nt], 0, 0, 0);                                 \
        }                                                                       \
    }

__global__ __launch_bounds__(NTHREADS, 2)
void lstm_mfma(const int* __restrict__ x, const unsigned short* __restrict__ embWp8,
               const bf16x8* __restrict__ up, float* __restrict__ out) {
    // h: bf16 single buffer, byte-swizzle ^((row&7)<<4); 2 barriers/step.
    // c: packed fp16 in registers. U residency: kt0,kt1 LDS; kt2-4 REGISTERS;
    // kt5-7 streamed (2-deep). LDS 149.5KB -> 1 block/CU -> 256-VGPR budget.
    __shared__ __align__(16) unsigned short hb[RTILE * DD];          // 16384 B
    __shared__ int xs[RTILE * TSTEPS];                               //  2048 B
    __shared__ __align__(16) unsigned short BresU[8 * 8 * 64 * 8];   // 65536 B
    __shared__ __align__(16) unsigned short B1resU[8 * 8 * 64 * 8];  // 65536 B

    const int tid  = threadIdx.x;
    const int w    = tid >> 6;
    const int lane = tid & 63;
    const int l15  = lane & 15, lg = lane >> 4;
    const int base = blockIdx.x * RTILE;

    xs[tid] = x[base * TSTEPS + tid];

    f32x4 acc[2][8];          // 64 accumulator regs (AGPR side)
    f16x16 cst;               // 8 regs, packed fp16 cell state
#pragma unroll
    for (int i = 0; i < 16; ++i) cst[i] = (_Float16)0.f;

    const bf16x8* upw = up + w * 4096;    // this wave's 64KB packed U slice

    // ---- stage step-invariant U: kt0,kt1 -> LDS; kt2,kt3,kt4 -> registers ----
    {
        char* bp = (char*)BresU + w * 8192 + lane * 16;
#pragma unroll
        for (int nt = 0; nt < 8; ++nt)
            *(bf16x8*)(bp + nt * 1024) = upw[nt * 64 + lane];         // kt=0
        char* b1 = (char*)B1resU + w * 8192 + lane * 16;
#pragma unroll
        for (int nt = 0; nt < 8; ++nt)
            *(bf16x8*)(b1 + nt * 1024) = upw[(8 + nt) * 64 + lane];   // kt=1
    }
    bf16x8 bR2[8], bR3[8], bR4[8];        // 96 persistent VGPRs
    LOADB(bR2, 2) LOADB(bR3, 3) LOADB(bR4, 4)

    __syncthreads();

#pragma unroll 1
    for (int t = 0; t < TSTEPS; ++t) {
        // ---- acc init: z = embW[x_t] gather (bf16, +b folded) ----
#pragma unroll
        for (int mt = 0; mt < 2; ++mt) {
#pragma unroll
            for (int j = 0; j < 4; ++j) {
                const int r    = mt * 16 + lg * 4 + j;        // C/D row
                const int xrow = xs[r * TSTEPS + t];
                const u16x8 u =
                    *(const u16x8*)(embWp8 + ((xrow * 8 + w) * 16 + l15) * 8);
#pragma unroll
                for (int gg = 0; gg < 8; ++gg)
                    acc[mt][gg][j] = __uint_as_float((unsigned)u[gg] << 16);
            }
        }

        // ---- z += h @ U; kt0-1 LDS, kt2-4 regs, kt5-7 streamed 2-deep ----
        if (t > 0) {
            const char* rbb = (const char*)hb;
            bf16x8 bA[8], bB[8];
            LOADB(bA, 5) LOADB(bB, 6)     // 16 loads fly under 80 resident MFMAs
            AFR_LDSRES(0, BresU)
            AFR_LDSRES(1, B1resU)
            AFR_MFMA(2, bR2)
            AFR_MFMA(3, bR3)
            AFR_MFMA(4, bR4)
            AFR_MFMA(5, bA)
            LOADB(bA, 7)
            AFR_MFMA(6, bB)
            AFR_MFMA(7, bA)
        }

        __syncthreads();   // #1: all reads of h(t-1) complete before overwrite

        // ---- gate update (Keras i,f,g,o; identity candidate/output) ----
        {
            char* wbb = (char*)hb;
#pragma unroll
            for (int mt = 0; mt < 2; ++mt) {
#pragma unroll
                for (int nn = 0; nn < 2; ++nn) {
#pragma unroll
                    for (int j = 0; j < 4; ++j) {
                        const float zi = acc[mt][0 + nn][j];
                        const float zf = acc[mt][2 + nn][j];
                        const float zg = acc[mt][4 + nn][j];
                        const float zo = acc[mt][6 + nn][j];
                        const float ig = sigmoid_fast(zi);
                        const float fg = sigmoid_fast(zf);
                        const float og = sigmoid_fast(zo);
                        const int ci = mt * 8 + nn * 4 + j;
                        const float cn = fg * (float)cst[ci] + ig * zg;
                        cst[ci] = (_Float16)cn;
                        const float h = og * cn;
                        const int row = mt * 16 + lg * 4 + j;
                        const int d   = w * 32 + nn * 16 + l15;
                        *(unsigned short*)(wbb +
                            ((row * 512 + d * 2) ^ ((row & 7) << 4))) = f2bf_bits(h);
                        if (t == TSTEPS - 1) out[(base + row) * DD + d] = h;
                    }
                }
            }
        }
        __syncthreads();   // #2: h(t) visible for next step's A-reads
    }
}

extern "C" void kernel_launch(void* const* d_in, const int* in_sizes, int n_in,
                              void* d_out, int out_size, void* d_ws, size_t ws_size,
                              hipStream_t stream) {
    const int*   x   = (const int*)d_in[0];
    const float* emb = (const float*)d_in[1];
    const float* W   = (const float*)d_in[2];
    const float* U   = (const float*)d_in[3];
    const float* b   = (const float*)d_in[4];
    float* out = (float*)d_out;

    unsigned short* embWp8 = (unsigned short*)d_ws;        // 317KB
    bf16x8*         up     = (bf16x8*)((char*)d_ws + (1 << 20));   // 512KB at +1MB

    embw_kernel<<<NCHAR, 256, 0, stream>>>(emb, W, b, embWp8);
    upack_kernel<<<128, 256, 0, stream>>>(U, up);
    lstm_mfma<<<NBLOCKS, NTHREADS, 0, stream>>>(x, embWp8, up, out);
}

// Round 16
// 113.704 us; speedup vs baseline: 1.2609x; 1.2609x over previous
//
#include <hip/hip_runtime.h>
#include <hip/hip_bf16.h>

// EmbeddingRNN via MFMA — FINAL (revert to round-14 verified optimum, 113.4us).
// R15 post-mortem: 512-thr blocks are hard-capped at 128 VGPR (4 independent
// confirmations R5/R6/R13/R15); register U-residency beyond ~124 live spills.
// R14 sits AT the empirical per-CU global->reg staging wall (~26 B/cy/CU,
// matching m97/m201/HipKittens/hipBLASLt staging rates on gfx950):
//   448KB/step x 4096 block-steps / (256CU x 26B/cy x 2.4GHz) ~= 115us.
// Byte floor is pinned: U column slices are wave-disjoint (no LDS sharing
// possible), LDS residency maxed (kt0+kt1 = 128KB of 160), register residency
// walled, fp8/MX-fp8 U fails the 1.4e-3 accuracy budget (e4m3 mantissa).
// Design: 256 blocks x 8 waves x 32 rows, 16 LSTM steps fused on-CU.
//   embW = emb@W+b precomputed (155x1024 bf16, gather kills the e@W GEMM);
//   U prepacked as bf16 MFMA B-fragments; kt0+kt1 LDS-resident, kt2-7
//   streamed 2-deep; h bf16 in swizzled LDS; c fp16 in registers;
//   sigmoid via v_rcp; WRITE_SIZE==8.2MB spill-meter clean.

#define DD      256
#define G4      1024
#define NCHAR   155
#define TSTEPS  16
#define RTILE   32
#define NROWS   8192
#define NBLOCKS (NROWS / RTILE)   // 256
#define NTHREADS 512              // 8 waves; wave w owns d-slice [w*32, w*32+32)

typedef __attribute__((ext_vector_type(8))) short bf16x8;
typedef __attribute__((ext_vector_type(8))) unsigned short u16x8;
typedef __attribute__((ext_vector_type(4))) float f32x4;
typedef __attribute__((ext_vector_type(16))) _Float16 f16x16;

__device__ inline unsigned short f2bf_bits(float f) {
    __hip_bfloat16 h = __float2bfloat16(f);   // RTNE
    return *reinterpret_cast<unsigned short*>(&h);
}

__device__ inline float sigmoid_fast(float x) {
    return __builtin_amdgcn_rcpf(1.f + __expf(-x));
}

// ---------------- phase 0a: embWp8 = pack_bf16(emb @ W + b) ----------------
// value (char i, gate g, col d): w=d>>5, l15=d&15, nn=(d>>4)&1, nt=g*2+nn
// embWp8[ ((i*8 + w)*16 + l15)*8 + nt ]  (ushort bf16)
__global__ __launch_bounds__(256)
void embw_kernel(const float* __restrict__ emb, const float* __restrict__ W,
                 const float* __restrict__ b, unsigned short* __restrict__ embWp8) {
    const int i   = blockIdx.x;
    const int tid = threadIdx.x;
    float a0 = b[tid], a1 = b[256 + tid], a2 = b[512 + tid], a3 = b[768 + tid];
    const float* er = emb + i * DD;
    for (int k = 0; k < DD; ++k) {
        const float e = er[k];
        const float* wr = W + k * G4 + tid;
        a0 += e * wr[0];
        a1 += e * wr[256];
        a2 += e * wr[512];
        a3 += e * wr[768];
    }
    const int w = tid >> 5, l15 = tid & 15, nn = (tid >> 4) & 1;
    unsigned short* o = embWp8 + ((i * 8 + w) * 16 + l15) * 8 + nn;
    o[0] = f2bf_bits(a0); o[2] = f2bf_bits(a1);
    o[4] = f2bf_bits(a2); o[6] = f2bf_bits(a3);   // nt = g*2+nn
}

// ---------------- phase 0b: pack U into bf16 MFMA B-fragments ----------------
// up[((w*8 + kt)*8 + nt)*64 + lane]: lane l holds
//   U[kt*32+(l>>4)*8+j][g*256 + w*32 + nn*16 + (l&15)], nt=g*2+nn
__global__ __launch_bounds__(256)
void upack_kernel(const float* __restrict__ U, bf16x8* __restrict__ up) {
    const int gid  = blockIdx.x * 256 + threadIdx.x;   // 32768 total
    const int lane = gid & 63;
    const int nt   = (gid >> 6) & 7;
    const int kt   = (gid >> 9) & 7;
    const int w    = gid >> 12;
    const int g = nt >> 1, nn = nt & 1;
    const int col = g * 256 + w * 32 + nn * 16 + (lane & 15);
    const int k0  = kt * 32 + (lane >> 4) * 8;
    bf16x8 v;
#pragma unroll
    for (int j = 0; j < 8; ++j) v[j] = (short)f2bf_bits(U[(k0 + j) * G4 + col]);
    up[gid] = v;
}

// ---------------- phase 1: fused recurrence ----------------

#define LOADB(DST, KT)                                                          \
    _Pragma("unroll")                                                           \
    for (int nt = 0; nt < 8; ++nt) (DST)[nt] = upw[((KT) * 8 + nt) * 64 + lane];

#define AFR_LOAD(KT)                                                            \
        const int kb = ((KT) * 32 + lg * 8) * 2;                                \
        const int r0 = l15, r1 = 16 + l15;                                      \
        bf16x8 afr0 = *(const bf16x8*)(rbb + ((r0 * 512 + kb) ^ ((r0 & 7) << 4))); \
        bf16x8 afr1 = *(const bf16x8*)(rbb + ((r1 * 512 + kb) ^ ((r1 & 7) << 4)));

// kt from global-loaded B regs
#define AFR_MFMA(KT, BARR)                                                      \
    {   AFR_LOAD(KT)                                                            \
        _Pragma("unroll")                                                       \
        for (int nt = 0; nt < 8; ++nt) {                                        \
            acc[0][nt] = __builtin_amdgcn_mfma_f32_16x16x32_bf16(               \
                afr0, (BARR)[nt], acc[0][nt], 0, 0, 0);                         \
            acc[1][nt] = __builtin_amdgcn_mfma_f32_16x16x32_bf16(               \
                afr1, (BARR)[nt], acc[1][nt], 0, 0, 0);                         \
        }                                                                       \
    }

// kt KT entirely from an LDS-resident tile (8 nt)
#define AFR_LDSRES(KT, BASE)                                                    \
    {   AFR_LOAD(KT)                                                            \
        const char* bp = (const char*)(BASE) + w * 8192 + lane * 16;            \
        _Pragma("unroll")                                                       \
        for (int nt = 0; nt < 8; ++nt) {                                        \
            bf16x8 bf = *(const bf16x8*)(bp + nt * 1024);                       \
            acc[0][nt] = __builtin_amdgcn_mfma_f32_16x16x32_bf16(               \
                afr0, bf, acc[0][nt], 0, 0, 0);                                 \
            acc[1][nt] = __builtin_amdgcn_mfma_f32_16x16x32_bf16(               \
                afr1, bf, acc[1][nt], 0, 0, 0);                                 \
        }                                                                       \
    }

__global__ __launch_bounds__(NTHREADS)
void lstm_mfma(const int* __restrict__ x, const unsigned short* __restrict__ embWp8,
               const bf16x8* __restrict__ up, float* __restrict__ out) {
    // h: bf16 SINGLE buffer, byte-swizzle ^((row&7)<<4); 2 barriers/step.
    // c: packed fp16 in registers (f16x16). BresU/B1resU: kt0+kt1 resident.
    __shared__ __align__(16) unsigned short hb[RTILE * DD];          // 16384 B
    __shared__ int xs[RTILE * TSTEPS];                               //  2048 B
    __shared__ __align__(16) unsigned short BresU[8 * 8 * 64 * 8];   // 65536 B
    __shared__ __align__(16) unsigned short B1resU[8 * 8 * 64 * 8];  // 65536 B

    const int tid  = threadIdx.x;
    const int w    = tid >> 6;
    const int lane = tid & 63;
    const int l15  = lane & 15, lg = lane >> 4;
    const int base = blockIdx.x * RTILE;

    xs[tid] = x[base * TSTEPS + tid];

    f32x4 acc[2][8];          // 64 accumulator regs
    f16x16 cst;               // 8 regs, packed fp16 cell state
#pragma unroll
    for (int i = 0; i < 16; ++i) cst[i] = (_Float16)0.f;

    const bf16x8* upw = up + w * 4096;    // this wave's 64KB packed U slice

    // ---- stage step-invariant U tiles into LDS (wave-private regions) ----
    {
        char* bp = (char*)BresU + w * 8192 + lane * 16;
#pragma unroll
        for (int nt = 0; nt < 8; ++nt)
            *(bf16x8*)(bp + nt * 1024) = upw[nt * 64 + lane];         // kt=0
        char* b1 = (char*)B1resU + w * 8192 + lane * 16;
#pragma unroll
        for (int nt = 0; nt < 8; ++nt)
            *(bf16x8*)(b1 + nt * 1024) = upw[(8 + nt) * 64 + lane];   // kt=1
    }

    __syncthreads();

#pragma unroll 1
    for (int t = 0; t < TSTEPS; ++t) {
        // ---- acc init: z = embW[x_t] gather (bf16, +b folded) ----
#pragma unroll
        for (int mt = 0; mt < 2; ++mt) {
#pragma unroll
            for (int j = 0; j < 4; ++j) {
                const int r    = mt * 16 + lg * 4 + j;        // C/D row
                const int xrow = xs[r * TSTEPS + t];
                const u16x8 u =
                    *(const u16x8*)(embWp8 + ((xrow * 8 + w) * 16 + l15) * 8);
#pragma unroll
                for (int gg = 0; gg < 8; ++gg)
                    acc[mt][gg][j] = __uint_as_float((unsigned)u[gg] << 16);
            }
        }

        // ---- z += h @ U; kt0+kt1 LDS-resident; kt2..7 2-deep reg pipeline ----
        if (t > 0) {
            const char* rbb = (const char*)hb;
            bf16x8 bA[8], bB[8];
            LOADB(bA, 2) LOADB(bB, 3)         // 16 loads fly under 32 LDS MFMAs
            AFR_LDSRES(0, BresU)              // kt0: LDS only, starts instantly
            AFR_LDSRES(1, B1resU)             // kt1: LDS only
#pragma unroll 1
            for (int ktp = 0; ktp < 3; ++ktp) {
                const int kta = 2 * ktp + 2, ktb = kta + 1;   // (2,3)(4,5)(6,7)
                AFR_MFMA(kta, bA)
                if (ktp < 2) { LOADB(bA, kta + 2) }
                AFR_MFMA(ktb, bB)
                if (ktp < 2) { LOADB(bB, ktb + 2) }
            }
        }

        __syncthreads();   // #1: all reads of h(t-1) complete before overwrite

        // ---- gate update (Keras i,f,g,o; identity candidate/output) ----
        {
            char* wbb = (char*)hb;
#pragma unroll
            for (int mt = 0; mt < 2; ++mt) {
#pragma unroll
                for (int nn = 0; nn < 2; ++nn) {
#pragma unroll
                    for (int j = 0; j < 4; ++j) {
                        const float zi = acc[mt][0 + nn][j];
                        const float zf = acc[mt][2 + nn][j];
                        const float zg = acc[mt][4 + nn][j];
                        const float zo = acc[mt][6 + nn][j];
                        const float ig = sigmoid_fast(zi);
                        const float fg = sigmoid_fast(zf);
                        const float og = sigmoid_fast(zo);
                        const int ci = mt * 8 + nn * 4 + j;
                        const float cn = fg * (float)cst[ci] + ig * zg;
                        cst[ci] = (_Float16)cn;
                        const float h = og * cn;
                        const int row = mt * 16 + lg * 4 + j;
                        const int d   = w * 32 + nn * 16 + l15;
                        *(unsigned short*)(wbb +
                            ((row * 512 + d * 2) ^ ((row & 7) << 4))) = f2bf_bits(h);
                        if (t == TSTEPS - 1) out[(base + row) * DD + d] = h;
                    }
                }
            }
        }
        __syncthreads();   // #2: h(t) visible for next step's A-reads
    }
}

extern "C" void kernel_launch(void* const* d_in, const int* in_sizes, int n_in,
                              void* d_out, int out_size, void* d_ws, size_t ws_size,
                              hipStream_t stream) {
    const int*   x   = (const int*)d_in[0];
    const float* emb = (const float*)d_in[1];
    const float* W   = (const float*)d_in[2];
    const float* U   = (const float*)d_in[3];
    const float* b   = (const float*)d_in[4];
    float* out = (float*)d_out;

    unsigned short* embWp8 = (unsigned short*)d_ws;        // 317KB
    bf16x8*         up     = (bf16x8*)((char*)d_ws + (1 << 20));   // 512KB at +1MB

    embw_kernel<<<NCHAR, 256, 0, stream>>>(emb, W, b, embWp8);
    upack_kernel<<<128, 256, 0, stream>>>(U, up);
    lstm_mfma<<<NBLOCKS, NTHREADS, 0, stream>>>(x, embWp8, up, out);
}